// Round 6
// baseline (187.540 us; speedup 1.0000x reference)
//
#include <hip/hip_runtime.h>
#include <hip/hip_bf16.h>
#include <stdint.h>

#define B_    4
#define N_    8192
#define K_    32
#define CX    67      // 3 + C_IN
#define CMID  64
#define COUT  128

#define W1S   100     // W1 LDS row stride (elems): 50 words, 18 mod 32 -> conflict-free b128
#define W2S   72      // W2 row stride (elems): 36 words, 4 mod 32 -> ~conflict-free b128
#define TPG   4       // points per wave per WG (must divide 2048)
#define NWG   2048
#define GMAX  8191

#define W1E   (64 * W1S)              // 6400 elems
#define SMEME (W1E + 128 * W2S)       // 15616 elems = 31232 B

typedef __bf16 bf16_t;
typedef bf16_t bf16x8 __attribute__((ext_vector_type(8)));
typedef float  f32x4  __attribute__((ext_vector_type(4)));

__device__ __forceinline__ uint32_t pack2bf(float a, float b) {
    union { bf16_t h[2]; uint32_t u; } x;
    x.h[0] = (bf16_t)a; x.h[1] = (bf16_t)b;
    return x.u;
}

template<bool DIRECT>
__global__ __launch_bounds__(256, 3)
void sa_main(const float* __restrict__ dp, const float* __restrict__ fj,
             const float* __restrict__ W1, const float* __restrict__ b1,
             const float* __restrict__ W2, const float* __restrict__ b2,
             float* __restrict__ dst)
{
    __shared__ bf16_t smem[SMEME];

    const int tid  = threadIdx.x;
    const int wave = tid >> 6;
    const int lane = tid & 63;
    const int lrow = lane & 15;   // MFMA row/col within 16-tile
    const int g    = lane >> 4;   // 16-lane group (fragment k-group)

    const size_t plane = (size_t)N_ * K_;
    const int bidx = blockIdx.x;
    const int b    = (bidx * TPG) >> 11;   // batch constant per WG

    const float* dpb = dp + (size_t)b * 3  * plane;
    const float* fjb = fj + (size_t)b * 64 * plane;

    // per-lane channel-base pointers; chan = kc*32 + g*8 + e
    const float* baseA = (g == 0) ? dpb
                       : fjb + (ptrdiff_t)(8 * g - 3) * (ptrdiff_t)plane;   // kc=0, e=0..2
    const float* baseB = fjb + (ptrdiff_t)(8 * g - 3) * (ptrdiff_t)plane;   // kc=0, e=3..7
    const float* base1 = fjb + (size_t)(29 + 8 * g) * plane;                // kc=1, e=0..7
    const float* base2 = fjb + (size_t)61 * plane;                          // kc=2 (g==0, e<3)

    // landing: float2 per (chan, kpos-pair {2*lrow, 2*lrow+1}); two buffers (depth-2)
    float2 la[16], la2[3], lb[16], lb2[3];
    auto issue = [&](float2 (&v)[16], float2 (&v2)[3], int G) {
        const int n = ((G & 2047) << 2) + wave;
        const size_t off = (size_t)n * K_ + 2 * lrow;
        const float* pA = baseA + off;
        const float* pB = baseB + off;
        const float* p1 = base1 + off;
        #pragma unroll
        for (int e = 0; e < 3; ++e) v[e]     = *(const float2*)(pA + (size_t)e * plane);
        #pragma unroll
        for (int e = 3; e < 8; ++e) v[e]     = *(const float2*)(pB + (size_t)e * plane);
        #pragma unroll
        for (int e = 0; e < 8; ++e) v[8 + e] = *(const float2*)(p1 + (size_t)e * plane);
        v2[0] = v2[1] = v2[2] = make_float2(0.f, 0.f);
        if (g == 0) {   // exec-masked: pad channels never touch memory
            const float* p2 = base2 + off;
            #pragma unroll
            for (int e = 0; e < 3; ++e) v2[e] = *(const float2*)(p2 + (size_t)e * plane);
        }
    };

    // loads for t=0, t=1 in flight across the whole weight prologue
    {
        const int G0 = bidx * TPG;
        issue(la, la2, G0);
        issue(lb, lb2, G0 + 1 > GMAX ? GMAX : G0 + 1);
    }

    // ---- prologue: weights -> LDS ----
    // W1 rows PERMUTED: slot s=(rt*16 + 4q + i) holds chan pi = 32*(rt>>1) + 8q + 4*(rt&1) + i
    for (int i = tid; i < W1E; i += 256) {
        int s = i / W1S, c = i - s * W1S;
        int rt = s >> 4, r = s & 15, q = r >> 2, ii = r & 3;
        int o = 32 * (rt >> 1) + 8 * q + 4 * (rt & 1) + ii;
        smem[i] = (c < CX) ? (bf16_t)W1[o * CX + c] : (bf16_t)0.f;
    }
    // W2 [out][mid], zero-padded stride
    for (int i = tid; i < 128 * W2S; i += 256) {
        int o = i / W2S, c = i - o * W2S;
        smem[W1E + i] = (c < CMID) ? (bf16_t)W2[o * CMID + c] : (bf16_t)0.f;
    }
    __syncthreads();

    // b1 fragments, permuted to match W1 row order: b1f[rt][i] = b1[pi(rt, 4g+i)]
    f32x4 b1f[4];
    #pragma unroll
    for (int rt = 0; rt < 4; ++rt)
        b1f[rt] = *(const f32x4*)(b1 + 32 * (rt >> 1) + 8 * g + 4 * (rt & 1));
    float b2f[8];
    #pragma unroll
    for (int ot = 0; ot < 8; ++ot) b2f[ot] = b2[ot * 16 + lrow];

    const bf16_t* W2l = smem + W1E;

    auto point = [&](float2 (&v)[16], float2 (&v2)[3], int G) {
        const int n = ((G & 2047) << 2) + wave;

        // ---- cvt landing -> X B-frags (col s -> kpos 2s (f0) / 2s+1 (f1)) ----
        bf16x8 f0[3], f1[3];
        #pragma unroll
        for (int kc = 0; kc < 2; ++kc) {
            union { uint32_t u[4]; bf16x8 w; } c0, c1;
            #pragma unroll
            for (int p = 0; p < 4; ++p) {
                c0.u[p] = pack2bf(v[kc * 8 + 2 * p].x, v[kc * 8 + 2 * p + 1].x);
                c1.u[p] = pack2bf(v[kc * 8 + 2 * p].y, v[kc * 8 + 2 * p + 1].y);
            }
            f0[kc] = c0.w; f1[kc] = c1.w;
        }
        {
            union { uint32_t u[4]; bf16x8 w; } c0, c1;
            c0.u[0] = pack2bf(v2[0].x, v2[1].x); c0.u[1] = pack2bf(v2[2].x, 0.f);
            c0.u[2] = 0; c0.u[3] = 0;
            c1.u[0] = pack2bf(v2[0].y, v2[1].y); c1.u[1] = pack2bf(v2[2].y, 0.f);
            c1.u[2] = 0; c1.u[3] = 0;
            f0[2] = c0.w; f1[2] = c1.w;
        }
        // ---- reissue this buffer for G+2: in flight across ~2 compute phases ----
        { int Gn = G + 2; if (Gn > GMAX) Gn = GMAX; issue(v, v2, Gn); }

        // ---- layer 1: acc = W1(perm, LDS) * X(regs), both kpos halves ----
        f32x4 acc0[4] = {}, acc1v[4] = {};
        __builtin_amdgcn_s_setprio(1);
        #pragma unroll
        for (int kc = 0; kc < 3; ++kc) {
            #pragma unroll
            for (int rt = 0; rt < 4; ++rt) {
                bf16x8 wf = *(const bf16x8*)&smem[(rt * 16 + lrow) * W1S + kc * 32 + g * 8];
                acc0[rt]  = __builtin_amdgcn_mfma_f32_16x16x32_bf16(wf, f0[kc], acc0[rt], 0, 0, 0);
                acc1v[rt] = __builtin_amdgcn_mfma_f32_16x16x32_bf16(wf, f1[kc], acc1v[rt], 0, 0, 0);
            }
        }
        __builtin_amdgcn_s_setprio(0);

        // ---- epilogue 1: bias+relu -> pack -> layer-2 A-frags DIRECTLY (no LDS) ----
        // lane holds mids {32*kc2 + 8g .. +7} = exactly the x32 A-frag k-slots
        bf16x8 a2f0[2], a2f1[2];
        #pragma unroll
        for (int kc2 = 0; kc2 < 2; ++kc2) {
            union { uint32_t u[4]; bf16x8 w; } c0, c1;
            #pragma unroll
            for (int hh = 0; hh < 2; ++hh) {   // rt = 2*kc2 + hh
                const int rt = 2 * kc2 + hh;
                float h0 = fmaxf(acc0[rt][0] + b1f[rt][0], 0.f);
                float h1 = fmaxf(acc0[rt][1] + b1f[rt][1], 0.f);
                float h2 = fmaxf(acc0[rt][2] + b1f[rt][2], 0.f);
                float h3 = fmaxf(acc0[rt][3] + b1f[rt][3], 0.f);
                c0.u[hh * 2 + 0] = pack2bf(h0, h1);
                c0.u[hh * 2 + 1] = pack2bf(h2, h3);
                float j0 = fmaxf(acc1v[rt][0] + b1f[rt][0], 0.f);
                float j1 = fmaxf(acc1v[rt][1] + b1f[rt][1], 0.f);
                float j2 = fmaxf(acc1v[rt][2] + b1f[rt][2], 0.f);
                float j3 = fmaxf(acc1v[rt][3] + b1f[rt][3], 0.f);
                c1.u[hh * 2 + 0] = pack2bf(j0, j1);
                c1.u[hh * 2 + 1] = pack2bf(j2, j3);
            }
            a2f0[kc2] = c0.w; a2f1[kc2] = c1.w;
        }

        // ---- layer 2: A = packed H (regs), B = W2 (LDS); D cols = out chans ----
        float macc[8];
        __builtin_amdgcn_s_setprio(1);
        #pragma unroll
        for (int ot = 0; ot < 8; ++ot) {
            bf16x8 w20 = *(const bf16x8*)&W2l[(ot * 16 + lrow) * W2S +  0 + g * 8];
            bf16x8 w21 = *(const bf16x8*)&W2l[(ot * 16 + lrow) * W2S + 32 + g * 8];
            f32x4 t0 = {}, t1 = {};
            t0 = __builtin_amdgcn_mfma_f32_16x16x32_bf16(a2f0[0], w20, t0, 0, 0, 0);
            t0 = __builtin_amdgcn_mfma_f32_16x16x32_bf16(a2f0[1], w21, t0, 0, 0, 0);
            t1 = __builtin_amdgcn_mfma_f32_16x16x32_bf16(a2f1[0], w20, t1, 0, 0, 0);
            t1 = __builtin_amdgcn_mfma_f32_16x16x32_bf16(a2f1[1], w21, t1, 0, 0, 0);
            float m0 = fmaxf(fmaxf(t0[0], t0[1]), fmaxf(t0[2], t0[3]));
            float m1 = fmaxf(fmaxf(t1[0], t1[1]), fmaxf(t1[2], t1[3]));
            macc[ot] = fmaxf(m0, m1);   // in-lane pool over this lane's 4+4 kpos
        }
        __builtin_amdgcn_s_setprio(0);

        // ---- cross-group pool (xor16 + xor32), bias, relu ----
        #pragma unroll
        for (int ot = 0; ot < 8; ++ot) {
            float vv = macc[ot];
            vv = fmaxf(vv, __shfl_xor(vv, 16, 64));
            vv = fmaxf(vv, __shfl_xor(vv, 32, 64));
            macc[ot] = fmaxf(vv + b2f[ot], 0.f);
        }
        float oa = (g == 0) ? macc[0] : (g == 1) ? macc[2] : (g == 2) ? macc[4] : macc[6];
        float ob = (g == 0) ? macc[1] : (g == 1) ? macc[3] : (g == 2) ? macc[5] : macc[7];
        const int ca = g * 32 + lrow;
        const int cb = g * 32 + 16 + lrow;
        if (DIRECT) {
            float* op = dst + (size_t)b * COUT * N_ + n;
            op[(size_t)ca * N_] = oa;
            op[(size_t)cb * N_] = ob;
        } else {
            float* wp = dst + ((size_t)(b * N_ + n)) * COUT;   // ws[b][n][c]
            wp[ca] = oa;
            wp[cb] = ob;
        }
    };

    #pragma unroll 1
    for (int t = 0; t < TPG; t += 2) {
        const int G = bidx * TPG + t;
        point(la, la2, G);
        point(lb, lb2, G + 1);
    }
}

// ws[b][n][c] -> out[b][c][n], full lines on both sides
__global__ __launch_bounds__(256)
void sa_transpose(const float* __restrict__ ws, float* __restrict__ out)
{
    __shared__ float tile[32][136];
    const int t  = threadIdx.x;
    const int i  = blockIdx.x;         // 0..1023
    const int b  = i >> 8;
    const int n0 = (i & 255) << 5;

    const float* rp = ws + ((size_t)(b * N_ + n0)) * COUT;
    #pragma unroll
    for (int r = 0; r < 4; ++r) {
        int flat = (r * 256 + t) * 4;
        int nl = flat >> 7, c = flat & 127;
        float4 v = *(const float4*)(rp + (size_t)nl * COUT + c);
        *(float4*)&tile[nl][c] = v;
    }
    __syncthreads();
    float* op = out + (size_t)b * COUT * N_ + n0;
    const int nl4 = (t & 7) << 2;
    #pragma unroll
    for (int r2 = 0; r2 < 4; ++r2) {
        int c = r2 * 32 + (t >> 3);
        float4 o4;
        o4.x = tile[nl4 + 0][c];
        o4.y = tile[nl4 + 1][c];
        o4.z = tile[nl4 + 2][c];
        o4.w = tile[nl4 + 3][c];
        *(float4*)(op + (size_t)c * N_ + nl4) = o4;
    }
}

extern "C" void kernel_launch(void* const* d_in, const int* in_sizes, int n_in,
                              void* d_out, int out_size, void* d_ws, size_t ws_size,
                              hipStream_t stream) {
    // inputs: 0=p (unused), 1=f (unused), 2=dp, 3=fj, 4=W1, 5=b1, 6=W2, 7=b2
    const float* dp = (const float*)d_in[2];
    const float* fj = (const float*)d_in[3];
    const float* W1 = (const float*)d_in[4];
    const float* b1 = (const float*)d_in[5];
    const float* W2 = (const float*)d_in[6];
    const float* b2 = (const float*)d_in[7];
    float* out = (float*)d_out;

    const size_t ws_need = (size_t)B_ * N_ * COUT * sizeof(float);
    if (ws_size >= ws_need) {
        float* ws = (float*)d_ws;
        hipLaunchKernelGGL((sa_main<false>), dim3(NWG), dim3(256), 0, stream,
                           dp, fj, W1, b1, W2, b2, ws);
        hipLaunchKernelGGL(sa_transpose, dim3(1024), dim3(256), 0, stream, ws, out);
    } else {
        hipLaunchKernelGGL((sa_main<true>), dim3(NWG), dim3(256), 0, stream,
                           dp, fj, W1, b1, W2, b2, out);
    }
}